// Round 8
// baseline (217.588 us; speedup 1.0000x reference)
//
#include <hip/hip_runtime.h>

#define B_SZ 4096
#define S_SZ 128
#define XD 5
#define EH 128
#define DH 256
#define DSTEPS 10

typedef short v8s __attribute__((ext_vector_type(8)));
typedef float v4f __attribute__((ext_vector_type(4)));

__device__ __forceinline__ float bf2f(unsigned short u) {
    union { unsigned int i; float f; } v; v.i = ((unsigned int)u) << 16; return v.f;
}
__device__ __forceinline__ unsigned short f2bf(float f) {
    union { float f; unsigned int i; } v; v.f = f;
    unsigned int x = v.i;
    return (unsigned short)((x + 0x7FFFu + ((x >> 16) & 1u)) >> 16);
}
__device__ __forceinline__ float fexp2(float x) { return __builtin_amdgcn_exp2f(x); }
__device__ __forceinline__ float frcp(float x) { return __builtin_amdgcn_rcpf(x); }
__device__ __forceinline__ float sigmoidf_(float x) {
    return frcp(1.f + fexp2(-1.44269504088896f * x));
}
__device__ __forceinline__ float tanhf_(float x) {
    float e = fexp2(2.88539008177793f * x);   // e^(2x)
    return 1.f - 2.f * frcp(e + 1.f);
}

// ---------------------------------------------------------------- encoder
// (unchanged: r2 core + absorbed weight-prep side-job)
__global__ __launch_bounds__(512) void enc_kernel(
    const float* __restrict__ x,       // [B][S][5] fp32
    const float* __restrict__ Wih32,   // [384][5] fp32
    const float* __restrict__ Whh32,   // [384][128] fp32
    const float* __restrict__ bih,     // [384] fp32
    const float* __restrict__ bhh,     // [384] fp32
    const float* __restrict__ dWih,    // [768][129] fp32
    const float* __restrict__ dWhh,    // [768][256] fp32
    unsigned short* __restrict__ wihp,     // out: [768][136] bf16 (col128=y wt)
    unsigned short* __restrict__ dWhh_bf,  // out: [768][256] bf16
    unsigned short* __restrict__ ctex)     // out: [B][128] bf16
{
    __shared__ unsigned short xs[S_SZ][16][8];     // 32 KB
    __shared__ unsigned short hb[2][16][136];      // 8.5 KB, +8 pad
    __shared__ unsigned short zpad[8];

    const int tid = threadIdx.x;
    const int bid = blockIdx.x;
    const int wv = tid >> 6;
    const int lane = tid & 63;
    const int n = lane & 15;
    const int kg = lane >> 4;       // K-group / C-row quad
    const int r0 = bid * 16;

    // side-job: decoder weight conversion (grid-stride over 131072 threads)
    for (int i = bid * 512 + tid; i < 768 * 256; i += 131072)
        dWhh_bf[i] = f2bf(dWhh[i]);
    for (int i = bid * 512 + tid; i < 768 * 136; i += 131072) {
        int col = i / 136, k = i - col * 136;
        wihp[i] = (k < 129) ? f2bf(dWih[col * 129 + k]) : (unsigned short)0;
    }

    for (int i = tid; i < 2 * 16 * 136; i += 512) ((unsigned short*)hb)[i] = 0;
    if (tid < 8) zpad[tid] = 0;
    for (int i = tid; i < 16 * S_SZ * 8; i += 512) {
        int m = i >> 10;
        int rem = i & 1023;
        int t = rem >> 3;
        int j = rem & 7;
        unsigned short v = 0;
        if (j < XD) v = f2bf(x[(size_t)(r0 + m) * (S_SZ * XD) + t * XD + j]);
        xs[t][m][j] = v;
    }

    const int colw = wv * 16 + n;
    v8s fw[3][4];
    v8s fx[3];
    #pragma unroll
    for (int g = 0; g < 3; ++g) {
        int gcol = g * EH + colw;
        #pragma unroll
        for (int kt = 0; kt < 4; ++kt) {
            const float* p = &Whh32[(size_t)gcol * EH + kt * 32 + kg * 8];
            float4 lo = *(const float4*)p;
            float4 hi = *(const float4*)(p + 4);
            v8s f;
            f[0] = (short)f2bf(lo.x); f[1] = (short)f2bf(lo.y);
            f[2] = (short)f2bf(lo.z); f[3] = (short)f2bf(lo.w);
            f[4] = (short)f2bf(hi.x); f[5] = (short)f2bf(hi.y);
            f[6] = (short)f2bf(hi.z); f[7] = (short)f2bf(hi.w);
            fw[g][kt] = f;
        }
        v8s t = {0, 0, 0, 0, 0, 0, 0, 0};
        if (kg == 0) {
            const float* p = &Wih32[gcol * XD];
            #pragma unroll
            for (int j = 0; j < XD; ++j) t[j] = (short)f2bf(p[j]);
        }
        fx[g] = t;
    }
    const float b_r  = bih[colw]          + bhh[colw];
    const float b_z  = bih[EH + colw]     + bhh[EH + colw];
    const float bi_n = bih[2 * EH + colw];
    const float bh_n = bhh[2 * EH + colw];

    float hst[4] = {0.f, 0.f, 0.f, 0.f};
    __syncthreads();

    #pragma unroll 2
    for (int t = 0; t < S_SZ; ++t) {
        const int p = t & 1;
        v8s a[4];
        #pragma unroll
        for (int kt = 0; kt < 4; ++kt)
            a[kt] = *(const v8s*)&hb[p][n][kt * 32 + kg * 8];
        const unsigned short* xsrc = (kg == 0) ? &xs[t][n][0] : &zpad[0];
        v8s ax = *(const v8s*)xsrc;

        v4f accr  = {b_r, b_r, b_r, b_r};
        v4f accz  = {b_z, b_z, b_z, b_z};
        v4f acchn = {bh_n, bh_n, bh_n, bh_n};
        v4f accin = {bi_n, bi_n, bi_n, bi_n};
        #pragma unroll
        for (int kt = 0; kt < 4; ++kt) {
            accr  = __builtin_amdgcn_mfma_f32_16x16x32_bf16(a[kt], fw[0][kt], accr, 0, 0, 0);
            accz  = __builtin_amdgcn_mfma_f32_16x16x32_bf16(a[kt], fw[1][kt], accz, 0, 0, 0);
            acchn = __builtin_amdgcn_mfma_f32_16x16x32_bf16(a[kt], fw[2][kt], acchn, 0, 0, 0);
        }
        accr  = __builtin_amdgcn_mfma_f32_16x16x32_bf16(ax, fx[0], accr, 0, 0, 0);
        accz  = __builtin_amdgcn_mfma_f32_16x16x32_bf16(ax, fx[1], accz, 0, 0, 0);
        accin = __builtin_amdgcn_mfma_f32_16x16x32_bf16(ax, fx[2], accin, 0, 0, 0);

        #pragma unroll
        for (int e = 0; e < 4; ++e) {
            float r = sigmoidf_(accr[e]);
            float z = sigmoidf_(accz[e]);
            float nn = tanhf_(accin[e] + r * acchn[e]);
            float h = (1.f - z) * nn + z * hst[e];
            hst[e] = h;
            hb[1 - p][kg * 4 + e][colw] = f2bf(h);
        }
        __syncthreads();
    }
    #pragma unroll
    for (int e = 0; e < 4; ++e)
        ctex[(size_t)(r0 + kg * 4 + e) * EH + colw] = f2bf(hst[e]);
}

// ---------------------------------------------------------------- fused decoder v3
// r7 structure, register-pressure-safe: only cg=0 r/z B-frags resident
// (64 VGPRs, pinned); cg=1 r/z streamed from L2 inside the kt loop
// (128KB/block/step, L2-hot). t-loop unroll DISABLED so 10 iterations
// can't merge live ranges (r6/r7's suspected spill/remat source).
__global__ __launch_bounds__(512)
__attribute__((amdgpu_waves_per_eu(2, 2)))
void dec_all_kernel(
    const unsigned short* __restrict__ dWhh_bf, // [768][256] bf16
    const unsigned short* __restrict__ wihp,    // [768][136] bf16
    const float* __restrict__ dbih,   // [768]
    const float* __restrict__ dbhh,   // [768]
    const float* __restrict__ y,      // [B][128] fp32
    const unsigned short* __restrict__ ctex,  // [B][128] bf16
    const float* __restrict__ linW,   // [4][256] fp32
    const float* __restrict__ linb,   // [4] fp32
    float* __restrict__ out)          // [B][S][4] fp32
{
    __shared__ unsigned short wshn[32 * 264 * 8];  // 132 KB n-gate Whh (frag, pad 264)
    __shared__ unsigned short hshf[32 * 16 * 8];   // 8 KB   h state (frag)
    __shared__ unsigned short lwf[32 * 16 * 8];    // 8 KB   linW (frag, 4->16 pad)

    const int tid  = threadIdx.x;
    const int w    = tid >> 6;
    const int lane = tid & 63;
    const int n    = lane & 15;
    const int kg   = lane >> 4;
    const int rb   = blockIdx.x * 16;
    const int cbase = w * 32;

    // stage n-gate Whh (once; coalesced global reads)
    for (int i = tid; i < 256 * 32; i += 512) {
        int col = i >> 5, kgrp = i & 31;
        uint4 v = *(const uint4*)&dWhh_bf[(size_t)(512 + col) * 256 + kgrp * 8];
        *(uint4*)&wshn[(kgrp * 264 + col) * 8] = v;
    }
    // stage linW into frag layout
    {
        int col = tid >> 5, kgrp = tid & 31;
        unsigned short v8[8];
        #pragma unroll
        for (int j = 0; j < 8; ++j)
            v8[j] = (col < 4) ? f2bf(linW[col * 256 + kgrp * 8 + j]) : (unsigned short)0;
        *(uint4*)&lwf[(kgrp * 16 + col) * 8] = *(uint4*)v8;
    }
    // h0 = 1
    for (int i = tid; i < 32 * 16 * 8; i += 512) hshf[i] = 0x3F80;

    // resident r/z B-frags for cg=0 only: 2 gates x 8 K-tiles = 64 VGPRs
    v8s fB[2][8];
    #pragma unroll
    for (int g = 0; g < 2; ++g)
        #pragma unroll
        for (int kt = 0; kt < 8; ++kt)
            fB[g][kt] = *(const v8s*)
                &dWhh_bf[(size_t)(g * DH + cbase + n) * DH + kt * 32 + kg * 8];
    #pragma unroll
    for (int g = 0; g < 2; ++g)
        #pragma unroll
        for (int kt = 0; kt < 8; ++kt)
            asm volatile("" : "+v"(fB[g][kt]));   // forbid remat of these loads

    // cg=1 r/z stream base pointers (per-lane)
    const unsigned short* pR1 = &dWhh_bf[(size_t)(0 * DH + cbase + 16 + n) * DH + kg * 8];
    const unsigned short* pZ1 = &dWhh_bf[(size_t)(1 * DH + cbase + 16 + n) * DH + kg * 8];

    // gi = ctex @ dWih[:, :128]^T + dbih (+dbhh for r,z); y weight per col
    v4f gi[3][2];
    float wy[3][2], bNh[2];
    #pragma unroll
    for (int g = 0; g < 3; ++g)
        #pragma unroll
        for (int cg = 0; cg < 2; ++cg) {
            int gcol = g * DH + cbase + cg * 16 + n;
            float bb = dbih[gcol] + ((g < 2) ? dbhh[gcol] : 0.f);
            gi[g][cg] = (v4f){bb, bb, bb, bb};
            wy[g][cg] = bf2f(wihp[(size_t)gcol * 136 + 128]);
        }
    #pragma unroll
    for (int cg = 0; cg < 2; ++cg)
        bNh[cg] = dbhh[2 * DH + cbase + cg * 16 + n];

    #pragma unroll
    for (int kt = 0; kt < 4; ++kt) {
        v8s a = *(const v8s*)&ctex[(size_t)(rb + n) * EH + kt * 32 + kg * 8];
        #pragma unroll
        for (int g = 0; g < 3; ++g)
            #pragma unroll
            for (int cg = 0; cg < 2; ++cg) {
                v8s b = *(const v8s*)
                    &wihp[(size_t)(g * DH + cbase + cg * 16 + n) * 136 + kt * 32 + kg * 8];
                gi[g][cg] = __builtin_amdgcn_mfma_f32_16x16x32_bf16(a, b, gi[g][cg], 0, 0, 0);
            }
    }

    const float lb = (n < 4) ? linb[n] : 0.f;
    float hprev[2][4];
    #pragma unroll
    for (int cg = 0; cg < 2; ++cg)
        #pragma unroll
        for (int e = 0; e < 4; ++e) hprev[cg][e] = 1.0f;

    __syncthreads();

    #pragma clang loop unroll(disable)
    for (int t = 0; t < DSTEPS; ++t) {
        float yv[4];
        #pragma unroll
        for (int e = 0; e < 4; ++e)
            yv[e] = y[(size_t)(rb + kg * 4 + e) * S_SZ + t];

        v4f ar[2], az[2], an[2];
        #pragma unroll
        for (int cg = 0; cg < 2; ++cg) {
            ar[cg] = (v4f){0.f, 0.f, 0.f, 0.f};
            az[cg] = (v4f){0.f, 0.f, 0.f, 0.f};
            an[cg] = (v4f){bNh[cg], bNh[cg], bNh[cg], bNh[cg]};
        }
        #pragma unroll
        for (int kt = 0; kt < 8; ++kt) {
            v8s a   = *(const v8s*)&hshf[((kt * 4 + kg) * 16 + n) * 8];
            v8s br1 = *(const v8s*)&pR1[kt * 32];
            v8s bz1 = *(const v8s*)&pZ1[kt * 32];
            v8s bn0 = *(const v8s*)&wshn[((kt * 4 + kg) * 264 + cbase + n) * 8];
            v8s bn1 = *(const v8s*)&wshn[((kt * 4 + kg) * 264 + cbase + 16 + n) * 8];
            ar[0] = __builtin_amdgcn_mfma_f32_16x16x32_bf16(a, fB[0][kt], ar[0], 0, 0, 0);
            az[0] = __builtin_amdgcn_mfma_f32_16x16x32_bf16(a, fB[1][kt], az[0], 0, 0, 0);
            an[0] = __builtin_amdgcn_mfma_f32_16x16x32_bf16(a, bn0,      an[0], 0, 0, 0);
            ar[1] = __builtin_amdgcn_mfma_f32_16x16x32_bf16(a, br1,      ar[1], 0, 0, 0);
            az[1] = __builtin_amdgcn_mfma_f32_16x16x32_bf16(a, bz1,      az[1], 0, 0, 0);
            an[1] = __builtin_amdgcn_mfma_f32_16x16x32_bf16(a, bn1,      an[1], 0, 0, 0);
        }
        __syncthreads();   // all reads of h_t complete

        #pragma unroll
        for (int cg = 0; cg < 2; ++cg) {
            const int chi = 4 * w + 2 * cg + (n >> 3);   // (col>>3)
            #pragma unroll
            for (int e = 0; e < 4; ++e) {
                float r  = sigmoidf_(gi[0][cg][e] + yv[e] * wy[0][cg] + ar[cg][e]);
                float z  = sigmoidf_(gi[1][cg][e] + yv[e] * wy[1][cg] + az[cg][e]);
                float nn = tanhf_(gi[2][cg][e] + yv[e] * wy[2][cg] + r * an[cg][e]);
                float h  = nn + z * (hprev[cg][e] - nn);
                hprev[cg][e] = h;
                hshf[(chi * 16 + kg * 4 + e) * 8 + (n & 7)] = f2bf(h);
            }
        }
        __syncthreads();   // h_{t+1} visible

        if (w == 0) {      // out-proj (overlaps other waves' next MFMA phase)
            v4f o4 = {0.f, 0.f, 0.f, 0.f};
            #pragma unroll
            for (int kt = 0; kt < 8; ++kt) {
                v8s a = *(const v8s*)&hshf[((kt * 4 + kg) * 16 + n) * 8];
                v8s b = *(const v8s*)&lwf[((kt * 4 + kg) * 16 + n) * 8];
                o4 = __builtin_amdgcn_mfma_f32_16x16x32_bf16(a, b, o4, 0, 0, 0);
            }
            if (n < 4) {
                #pragma unroll
                for (int e = 0; e < 4; ++e)
                    out[(size_t)(rb + kg * 4 + e) * (S_SZ * 4) + t * 4 + n] = o4[e] + lb;
            }
        }
    }

    // tail pad: out[:, 10:, :] = 1.0
    for (int j = tid; j < 16 * 512; j += 512) {
        int row = j >> 9, c = j & 511;
        if (c >= DSTEPS * 4) out[(size_t)(rb + row) * 512 + c] = 1.0f;
    }
}

// ---------------------------------------------------------------- launch
extern "C" void kernel_launch(void* const* d_in, const int* in_sizes, int n_in,
                              void* d_out, int out_size, void* d_ws, size_t ws_size,
                              hipStream_t stream)
{
    const float* x    = (const float*)d_in[0];
    const float* y    = (const float*)d_in[1];
    const float* eWih = (const float*)d_in[2];
    const float* eWhh = (const float*)d_in[3];
    const float* ebih = (const float*)d_in[4];
    const float* ebhh = (const float*)d_in[5];
    const float* dWih = (const float*)d_in[6];
    const float* dWhh = (const float*)d_in[7];
    const float* dbih = (const float*)d_in[8];
    const float* dbhh = (const float*)d_in[9];
    const float* linW = (const float*)d_in[10];
    const float* linb = (const float*)d_in[11];
    float* out = (float*)d_out;

    char* ws = (char*)d_ws;
    // ws layout (bytes):
    //   wihp     @ 0      : 768*136*2 = 208896
    //   dWhh_bf  @ 208896 : 768*256*2 = 393216  -> 602112
    //   ctex     @ 602112 : 4096*128*2 = 1048576 -> 1650688
    unsigned short* wihp    = (unsigned short*)(ws);
    unsigned short* dWhh_bf = (unsigned short*)(ws + 208896);
    unsigned short* ctex    = (unsigned short*)(ws + 602112);

    enc_kernel<<<256, 512, 0, stream>>>(x, eWih, eWhh, ebih, ebhh,
                                        dWih, dWhh, wihp, dWhh_bf, ctex);
    dec_all_kernel<<<256, 512, 0, stream>>>(dWhh_bf, wihp, dbih, dbhh, y,
                                            ctex, linW, linb, out);
}